// Round 1
// baseline (1475.882 us; speedup 1.0000x reference)
//
#include <hip/hip_runtime.h>
#include <hip/hip_bf16.h>

// ---------------------------------------------------------------------------
// GATv2 x2 (PyG GATv2Conv semantics with self-loops), MI355X.
// Internal math fp32; intermediates bf16 where gathered. Input/out dtype is
// auto-detected (bf16 vs fp32) via a device-side probe -> flag in ws.
// ---------------------------------------------------------------------------

typedef unsigned short u16;

#define F_IN   128
#define CH     32
#define H1     8
#define JT1    512   // 2 * H1*CH  (xl | xr concatenated)
#define JH1    256   // H1*CH
#define JT2    64    // 2 * CH
#define JH2    32

// ---- ws layout (bytes) ----------------------------------------------------
// Region A (0..51.2M): Y1 [gemm1 -> edge1], then reused:
//   Y2 @0 (6.4M) [gemm2 -> edge2], out2 @8M [edge2 -> node2],
//   den2 @16M [edge2 -> node2], h @20M (25.6M) [node1 -> gemm2]
// Region B (52M..103.2M): XC @52M (12.8M) [cvt -> gemm1], then out1_raw
//   @52M (51.2M) [memset-after-gemm1 -> edge1 -> node1]
// den1 @104M (1.6M); canonical weights @105.7M; flag @105.9M
#define OFF_Y1    0UL
#define OFF_Y2    0UL
#define OFF_OUT2  8000000UL
#define OFF_DEN2  16000000UL
#define OFF_H     20000000UL
#define OFF_XC    52000000UL
#define OFF_OUT1  52000000UL
#define OFF_DEN1  104000000UL
#define OFF_WC    105700000UL
#define OFF_FLAG  105900000UL
#define WS_NEED   106000000UL

// canonical weight offsets (elements within Wc)
#define W_WL1   0
#define W_BL1   32768
#define W_WR1   33024
#define W_BR1   65792
#define W_ATT1  66048
#define W_BIAS1 66304
#define W_WL2   66560
#define W_BL2   74752
#define W_WR2   74784
#define W_BR2   82976
#define W_ATT2  83008
#define W_BIAS2 83040

__device__ inline float b2f(u16 u) { return __uint_as_float(((unsigned)u) << 16); }
__device__ inline u16 f2b(float f) {
    unsigned u = __float_as_uint(f);
    unsigned r = (u + 0x7fffu + ((u >> 16) & 1u)) >> 16;
    return (u16)r;
}

// ---------------------------------------------------------------------------
// dtype probe: count plausible-bf16 ushorts among first 512 of x.
// fp32 source -> even ushorts are mantissa bits (random exponent field) ->
// count ~ 290/512. bf16 source (values ~N(0,1)) -> count ~ 512.
// ---------------------------------------------------------------------------
__global__ void detect_dtype(const u16* __restrict__ x, int* __restrict__ flag) {
    int lane = threadIdx.x;
    int cnt = 0;
    for (int i = lane; i < 512; i += 64) {
        u16 u = x[i];
        int e = (u >> 7) & 0xff;
        cnt += (u == 0 || (e >= 100 && e <= 141)) ? 1 : 0;
    }
#pragma unroll
    for (int m = 32; m; m >>= 1) cnt += __shfl_xor(cnt, m);
    if (lane == 0) *flag = (cnt >= 440) ? 1 : 0;
}

// convert one float input array to canonical bf16
__global__ void cvt_bf16(const void* __restrict__ src, u16* __restrict__ dst,
                         int n, const int* __restrict__ flag) {
    int i = blockIdx.x * 256 + threadIdx.x;
    if (i >= n) return;
    if (*flag) dst[i] = ((const u16*)src)[i];
    else       dst[i] = f2b(((const float*)src)[i]);
}

// ---------------------------------------------------------------------------
// Y[m][2*JH] = X[m][K] @ [Wl;Wr][j][K]^T + [bl;br]   (all bf16 in, bf16 out)
// BM=32 nodes, BJ=64 cols per block; LDS padded to K+8 (stride = 4 words mod 32
// -> conflict-free for both x (per-node) and W (per-j) b128 reads).
// ---------------------------------------------------------------------------
template <int K>
__global__ __launch_bounds__(256) void gemm_node(
    const u16* __restrict__ X, const u16* __restrict__ Wl, const u16* __restrict__ Wr,
    const u16* __restrict__ bl, const u16* __restrict__ br,
    u16* __restrict__ Y, int M, int JH) {
    constexpr int SK = K + 8;
    __shared__ u16 xs[32 * SK];
    __shared__ u16 ws[64 * SK];
    const int m0 = blockIdx.x * 32;
    const int j0 = blockIdx.y * 64;
    const int t = threadIdx.x;
    const int JT = 2 * JH;

    constexpr int KV = K / 8;       // vec8 chunks per row
    constexpr int XV = 32 * KV;
    for (int v = t; v < XV; v += 256) {
        int row = v / KV, kv = v % KV;
        int gr = m0 + row; if (gr >= M) gr = M - 1;
        *(uint4*)&xs[row * SK + kv * 8] = *(const uint4*)(X + (size_t)gr * K + kv * 8);
    }
    constexpr int WV = 64 * KV;
    for (int v = t; v < WV; v += 256) {
        int row = v / KV, kv = v % KV;
        int jg = j0 + row;
        const u16* p = (jg < JH) ? (Wl + (size_t)jg * K) : (Wr + (size_t)(jg - JH) * K);
        *(uint4*)&ws[row * SK + kv * 8] = *(const uint4*)(p + kv * 8);
    }
    __syncthreads();

    const int node = t >> 3, jl = t & 7;
    float acc[8] = {0.f, 0.f, 0.f, 0.f, 0.f, 0.f, 0.f, 0.f};
#pragma unroll 4
    for (int k0 = 0; k0 < K; k0 += 8) {
        u16 xv[8];
        *(uint4*)xv = *(const uint4*)&xs[node * SK + k0];
        float xf[8];
#pragma unroll
        for (int i = 0; i < 8; i++) xf[i] = b2f(xv[i]);
#pragma unroll
        for (int jj = 0; jj < 8; jj++) {
            u16 wv[8];
            *(uint4*)wv = *(const uint4*)&ws[(jl + 8 * jj) * SK + k0];
#pragma unroll
            for (int i = 0; i < 8; i++) acc[jj] += xf[i] * b2f(wv[i]);
        }
    }
    const int gm = m0 + node;
    if (gm < M) {
#pragma unroll
        for (int jj = 0; jj < 8; jj++) {
            int j = j0 + jl + 8 * jj;
            float bias = b2f(j < JH ? bl[j] : br[j - JH]);
            Y[(size_t)gm * JT + j] = f2b(acc[jj] + bias);
        }
    }
}

// ---------------------------------------------------------------------------
// Layer-1 edge pass: one 32-lane group per edge (8 edges / 256-block).
// logit[h] = sum_c leaky(xl[src,h,c]+xr[dst,h,c]) * att[h,c]; e = exp(logit)
// (no max-subtraction: logits ~ N(0,1), exp safe in fp32).
// denom[dst,h] += e;  out_raw[dst,h,c] += e * xl[src,h,c]  (deferred division)
// ---------------------------------------------------------------------------
__global__ __launch_bounds__(256) void edge1(
    const u16* __restrict__ Y1, const int* __restrict__ ei,
    const u16* __restrict__ att, float* __restrict__ out_raw,
    float* __restrict__ denom, int E_, int NP) {
    const int g = threadIdx.x >> 5, lane = threadIdx.x & 31;
    const int e = blockIdx.x * 8 + g;
    if (e >= E_ + NP) return;
    int src, dst;
    if (e < E_) { src = ei[e]; dst = ei[E_ + e]; }
    else        { src = dst = e - E_; }
    const u16* xlp = Y1 + (size_t)src * JT1;
    const u16* xrp = Y1 + (size_t)dst * JT1 + JH1;
    float el[H1], xlv[H1];
#pragma unroll
    for (int h = 0; h < H1; h++) {
        float xl = b2f(xlp[h * 32 + lane]);
        float xr = b2f(xrp[h * 32 + lane]);
        xlv[h] = xl;
        float z = xl + xr;
        z = (z > 0.f) ? z : 0.2f * z;
        float p = z * b2f(att[h * 32 + lane]);
#pragma unroll
        for (int m = 16; m; m >>= 1) p += __shfl_xor(p, m);
        el[h] = __expf(p);
    }
    if (lane == 0) {
        float* d = denom + (size_t)dst * H1;
        atomicAdd(d + 0, el[0]); atomicAdd(d + 1, el[1]);
        atomicAdd(d + 2, el[2]); atomicAdd(d + 3, el[3]);
        atomicAdd(d + 4, el[4]); atomicAdd(d + 5, el[5]);
        atomicAdd(d + 6, el[6]); atomicAdd(d + 7, el[7]);
    }
    float* orow = out_raw + (size_t)dst * JH1;
#pragma unroll
    for (int h = 0; h < H1; h++)
        atomicAdd(orow + h * 32 + lane, el[h] * xlv[h]);
}

// node pass 1: h = gelu(out_raw/denom + bias1)   (exact gelu, erf)
__global__ __launch_bounds__(256) void node1(
    const float* __restrict__ out_raw, const float* __restrict__ denom,
    const u16* __restrict__ bias, u16* __restrict__ hout, int NN) {
    int idx = blockIdx.x * 256 + threadIdx.x;
    if (idx >= NN * JH1) return;
    int n = idx >> 8, j = idx & 255, h = j >> 5;
    float v = out_raw[idx] / fmaxf(denom[n * H1 + h], 1e-16f) + b2f(bias[j]);
    float gl = 0.5f * v * (1.f + erff(v * 0.70710678118654752f));
    hout[idx] = f2b(gl);
}

// Layer-2 edge pass: 1 head, 32 channels.
__global__ __launch_bounds__(256) void edge2(
    const u16* __restrict__ Y2, const int* __restrict__ ei,
    const u16* __restrict__ att, float* __restrict__ out_raw,
    float* __restrict__ denom, int E_, int NP) {
    const int g = threadIdx.x >> 5, lane = threadIdx.x & 31;
    const int e = blockIdx.x * 8 + g;
    if (e >= E_ + NP) return;
    int src, dst;
    if (e < E_) { src = ei[e]; dst = ei[E_ + e]; }
    else        { src = dst = e - E_; }
    float xl = b2f(Y2[(size_t)src * JT2 + lane]);
    float xr = b2f(Y2[(size_t)dst * JT2 + JH2 + lane]);
    float z = xl + xr;
    z = (z > 0.f) ? z : 0.2f * z;
    float p = z * b2f(att[lane]);
#pragma unroll
    for (int m = 16; m; m >>= 1) p += __shfl_xor(p, m);
    float el = __expf(p);
    if (lane == 0) atomicAdd(denom + dst, el);
    atomicAdd(out_raw + (size_t)dst * JH2 + lane, el * xl);
}

// node pass 2: out = out_raw/denom + bias2 ; store bf16 or fp32 per flag
__global__ __launch_bounds__(256) void node2(
    const float* __restrict__ out_raw, const float* __restrict__ denom,
    const u16* __restrict__ bias, void* __restrict__ dout, int NN,
    const int* __restrict__ flag) {
    int idx = blockIdx.x * 256 + threadIdx.x;
    if (idx >= NN * JH2) return;
    int n = idx >> 5, c = idx & 31;
    float v = out_raw[idx] / fmaxf(denom[n], 1e-16f) + b2f(bias[c]);
    if (*flag) ((u16*)dout)[idx] = f2b(v);
    else       ((float*)dout)[idx] = v;
}

extern "C" void kernel_launch(void* const* d_in, const int* in_sizes, int n_in,
                              void* d_out, int out_size, void* d_ws, size_t ws_size,
                              hipStream_t stream) {
    const int NN = in_sizes[0] / F_IN;   // 50000
    const int EE = in_sizes[1] / 2;      // 800000
    const int EP = EE + NN;              // edges + self loops
    if (ws_size < WS_NEED) return;       // loud fail: output stays zero

    char* w = (char*)d_ws;
    u16*   Y1   = (u16*)(w + OFF_Y1);
    u16*   Y2   = (u16*)(w + OFF_Y2);
    float* out2 = (float*)(w + OFF_OUT2);
    float* den2 = (float*)(w + OFF_DEN2);
    u16*   hbuf = (u16*)(w + OFF_H);
    u16*   XC   = (u16*)(w + OFF_XC);
    float* out1 = (float*)(w + OFF_OUT1);
    float* den1 = (float*)(w + OFF_DEN1);
    u16*   Wc   = (u16*)(w + OFF_WC);
    int*   flag = (int*)(w + OFF_FLAG);

    const int* ei = (const int*)d_in[1];

    // 1) dtype probe
    detect_dtype<<<1, 64, 0, stream>>>((const u16*)d_in[0], flag);

    // 2) canonicalize inputs to bf16
    auto cvt = [&](const void* src, u16* dst, int n) {
        cvt_bf16<<<(n + 255) / 256, 256, 0, stream>>>(src, dst, n, flag);
    };
    cvt(d_in[0],  XC,           NN * F_IN);
    cvt(d_in[2],  Wc + W_WL1,   JH1 * F_IN);
    cvt(d_in[3],  Wc + W_BL1,   JH1);
    cvt(d_in[4],  Wc + W_WR1,   JH1 * F_IN);
    cvt(d_in[5],  Wc + W_BR1,   JH1);
    cvt(d_in[6],  Wc + W_ATT1,  H1 * CH);
    cvt(d_in[7],  Wc + W_BIAS1, JH1);
    cvt(d_in[8],  Wc + W_WL2,   JH2 * JH1);
    cvt(d_in[9],  Wc + W_BL2,   JH2);
    cvt(d_in[10], Wc + W_WR2,   JH2 * JH1);
    cvt(d_in[11], Wc + W_BR2,   JH2);
    cvt(d_in[12], Wc + W_ATT2,  JH2);
    cvt(d_in[13], Wc + W_BIAS2, JH2);

    // 3) denom1 zero (independent region)
    hipMemsetAsync(den1, 0, (size_t)NN * H1 * 4, stream);

    // 4) layer-1 transform: Y1 = x @ [Wl1;Wr1]^T + b
    {
        dim3 grid((NN + 31) / 32, JT1 / 64);
        gemm_node<F_IN><<<grid, 256, 0, stream>>>(XC, Wc + W_WL1, Wc + W_WR1,
                                                  Wc + W_BL1, Wc + W_BR1, Y1, NN, JH1);
    }
    // 5) out1_raw zero (aliases XC -> must be after gemm1)
    hipMemsetAsync(out1, 0, (size_t)NN * JH1 * 4, stream);

    // 6) layer-1 edge pass
    edge1<<<(EP + 7) / 8, 256, 0, stream>>>(Y1, ei, Wc + W_ATT1, out1, den1, EE, NN);

    // 7) node pass 1 -> h (Y1 dead after edge1; h lives inside region A)
    node1<<<(NN * JH1 + 255) / 256, 256, 0, stream>>>(out1, den1, Wc + W_BIAS1, hbuf, NN);

    // 8) layer-2 transform: Y2 = h @ [Wl2;Wr2]^T + b
    {
        dim3 grid((NN + 31) / 32, JT2 / 64);
        gemm_node<JH1><<<grid, 256, 0, stream>>>(hbuf, Wc + W_WL2, Wc + W_WR2,
                                                 Wc + W_BL2, Wc + W_BR2, Y2, NN, JH2);
    }
    // 9) zero layer-2 accumulators (inside old Y1 region; edge1 done)
    hipMemsetAsync(out2, 0, (size_t)NN * JH2 * 4, stream);
    hipMemsetAsync(den2, 0, (size_t)NN * 4, stream);

    // 10) layer-2 edge pass
    edge2<<<(EP + 7) / 8, 256, 0, stream>>>(Y2, ei, Wc + W_ATT2, out2, den2, EE, NN);

    // 11) final node pass -> d_out (dtype per flag)
    node2<<<(NN * JH2 + 255) / 256, 256, 0, stream>>>(out2, den2, Wc + W_BIAS2,
                                                      d_out, NN, flag);
}

// Round 2
// 632.532 us; speedup vs baseline: 2.3333x; 2.3333x over previous
//
#include <hip/hip_runtime.h>
#include <hip/hip_bf16.h>

// ---------------------------------------------------------------------------
// GATv2 x2 (PyG GATv2Conv semantics with self-loops), MI355X.
// R2: CSR-by-dst gather aggregation (zero atomics in the hot path), fused
// softmax-normalize + bias + GELU epilogues into the aggregation kernels.
// ---------------------------------------------------------------------------

typedef unsigned short u16;

#define F_IN   128
#define CH     32
#define H1     8
#define JT1    512   // 2 * H1*CH  (xl | xr concatenated)
#define JH1    256   // H1*CH
#define JT2    64    // 2 * CH
#define JH2    32

// ---- ws layout (bytes) ----------------------------------------------------
// Y1 @0 (51.2M)  [gemm1 -> agg1]
// XC @52M (12.8M) [cvt -> gemm1]; h @52M (25.6M) [agg1 -> gemm2] (XC dead)
// Y2 @78M (6.4M) [gemm2 -> agg2]
// col @85M (3.4M); deg @89M; rowptr @89.4M; cur @89.8M; Wc @90.2M; flag @90.6M
#define OFF_Y1     0UL
#define OFF_XC     52000000UL
#define OFF_H      52000000UL
#define OFF_Y2     78000000UL
#define OFF_COL    85000000UL
#define OFF_DEG    89000000UL
#define OFF_ROW    89400000UL
#define OFF_CUR    89800000UL
#define OFF_WC     90200000UL
#define OFF_FLAG   90600000UL
#define WS_NEED    91000000UL

// canonical weight offsets (elements within Wc), cumulative in input order
#define W_WL1   0
#define W_BL1   32768
#define W_WR1   33024
#define W_BR1   65792
#define W_ATT1  66048
#define W_BIAS1 66304
#define W_WL2   66560
#define W_BL2   74752
#define W_WR2   74784
#define W_BR2   82976
#define W_ATT2  83008
#define W_BIAS2 83040
#define W_TOTAL 83072

__device__ inline float b2f(u16 u) { return __uint_as_float(((unsigned)u) << 16); }
__device__ inline u16 f2b(float f) {
    unsigned u = __float_as_uint(f);
    unsigned r = (u + 0x7fffu + ((u >> 16) & 1u)) >> 16;
    return (u16)r;
}

// ---------------------------------------------------------------------------
// dtype probe (unchanged from R1, verified working)
// ---------------------------------------------------------------------------
__global__ void detect_dtype(const u16* __restrict__ x, int* __restrict__ flag) {
    int lane = threadIdx.x;
    int cnt = 0;
    for (int i = lane; i < 512; i += 64) {
        u16 u = x[i];
        int e = (u >> 7) & 0xff;
        cnt += (u == 0 || (e >= 100 && e <= 141)) ? 1 : 0;
    }
#pragma unroll
    for (int m = 32; m; m >>= 1) cnt += __shfl_xor(cnt, m);
    if (lane == 0) *flag = (cnt >= 440) ? 1 : 0;
}

__global__ void cvt_bf16(const void* __restrict__ src, u16* __restrict__ dst,
                         int n, const int* __restrict__ flag) {
    int i = blockIdx.x * 256 + threadIdx.x;
    if (i >= n) return;
    if (*flag) dst[i] = ((const u16*)src)[i];
    else       dst[i] = f2b(((const float*)src)[i]);
}

struct WcArgs { const void* src[12]; int cum[13]; };

__global__ void cvt_weights(WcArgs a, u16* __restrict__ dst, int total,
                            const int* __restrict__ flag) {
    int i = blockIdx.x * 256 + threadIdx.x;
    if (i >= total) return;
    int s = 0;
    while (i >= a.cum[s + 1]) s++;
    int rel = i - a.cum[s];
    if (*flag) dst[i] = ((const u16*)a.src[s])[rel];
    else       dst[i] = f2b(((const float*)a.src[s])[rel]);
}

// ---------------------------------------------------------------------------
// CSR build: deg histogram -> single-block scan -> cursor scatter
// ---------------------------------------------------------------------------
__global__ void build_deg(const int* __restrict__ ei, int* __restrict__ deg,
                          int E_, int NP) {
    int e = blockIdx.x * 256 + threadIdx.x;
    if (e >= E_ + NP) return;
    int dst = (e < E_) ? ei[E_ + e] : e - E_;
    atomicAdd(deg + dst, 1);
}

__global__ __launch_bounds__(1024) void scan_deg(const int* __restrict__ deg,
                                                 int* __restrict__ rowptr,
                                                 int* __restrict__ cur, int NN) {
    int t = threadIdx.x;
    int chunk = (NN + 1023) >> 10;
    int beg = t * chunk, end = min(beg + chunk, NN);
    int s = 0;
    for (int i = beg; i < end; i++) s += deg[i];
    __shared__ int ps[1024];
    ps[t] = s; __syncthreads();
    for (int off = 1; off < 1024; off <<= 1) {
        int x = (t >= off) ? ps[t - off] : 0;
        __syncthreads();
        ps[t] += x;
        __syncthreads();
    }
    int run = t ? ps[t - 1] : 0;
    for (int i = beg; i < end; i++) { rowptr[i] = run; cur[i] = run; run += deg[i]; }
    if (t == 1023) rowptr[NN] = ps[1023];
}

__global__ void scatter_edges(const int* __restrict__ ei, int* __restrict__ cur,
                              int* __restrict__ col, int E_, int NP) {
    int e = blockIdx.x * 256 + threadIdx.x;
    if (e >= E_ + NP) return;
    int src, dst;
    if (e < E_) { src = ei[e]; dst = ei[E_ + e]; }
    else        { src = dst = e - E_; }
    int pos = atomicAdd(cur + dst, 1);
    col[pos] = src;
}

// ---------------------------------------------------------------------------
// Y[m][2*JH] = X[m][K] @ [Wl;Wr][j][K]^T + [bl;br]   (bf16 in/out, fp32 acc)
// ---------------------------------------------------------------------------
template <int K>
__global__ __launch_bounds__(256) void gemm_node(
    const u16* __restrict__ X, const u16* __restrict__ Wl, const u16* __restrict__ Wr,
    const u16* __restrict__ bl, const u16* __restrict__ br,
    u16* __restrict__ Y, int M, int JH) {
    constexpr int SK = K + 8;
    __shared__ u16 xs[32 * SK];
    __shared__ u16 ws[64 * SK];
    const int m0 = blockIdx.x * 32;
    const int j0 = blockIdx.y * 64;
    const int t = threadIdx.x;
    const int JT = 2 * JH;

    constexpr int KV = K / 8;
    constexpr int XV = 32 * KV;
    for (int v = t; v < XV; v += 256) {
        int row = v / KV, kv = v % KV;
        int gr = m0 + row; if (gr >= M) gr = M - 1;
        *(uint4*)&xs[row * SK + kv * 8] = *(const uint4*)(X + (size_t)gr * K + kv * 8);
    }
    constexpr int WV = 64 * KV;
    for (int v = t; v < WV; v += 256) {
        int row = v / KV, kv = v % KV;
        int jg = j0 + row;
        const u16* p = (jg < JH) ? (Wl + (size_t)jg * K) : (Wr + (size_t)(jg - JH) * K);
        *(uint4*)&ws[row * SK + kv * 8] = *(const uint4*)(p + kv * 8);
    }
    __syncthreads();

    const int node = t >> 3, jl = t & 7;
    float acc[8] = {0.f, 0.f, 0.f, 0.f, 0.f, 0.f, 0.f, 0.f};
#pragma unroll 4
    for (int k0 = 0; k0 < K; k0 += 8) {
        u16 xv[8];
        *(uint4*)xv = *(const uint4*)&xs[node * SK + k0];
        float xf[8];
#pragma unroll
        for (int i = 0; i < 8; i++) xf[i] = b2f(xv[i]);
#pragma unroll
        for (int jj = 0; jj < 8; jj++) {
            u16 wv[8];
            *(uint4*)wv = *(const uint4*)&ws[(jl + 8 * jj) * SK + k0];
#pragma unroll
            for (int i = 0; i < 8; i++) acc[jj] += xf[i] * b2f(wv[i]);
        }
    }
    const int gm = m0 + node;
    if (gm < M) {
#pragma unroll
        for (int jj = 0; jj < 8; jj++) {
            int j = j0 + jl + 8 * jj;
            float bias = b2f(j < JH ? bl[j] : br[j - JH]);
            Y[(size_t)gm * JT + j] = f2b(acc[jj] + bias);
        }
    }
}

// ---------------------------------------------------------------------------
// Layer-1 aggregate: one 64-lane wave per dst node. Lane owns 4 channels
// (head = lane>>3). Per edge: one coalesced 512B xl-row read, logit via
// 8-lane shuffle reduce, register accumulation. Fused /denom + bias + GELU.
// ---------------------------------------------------------------------------
__global__ __launch_bounds__(256) void agg1(
    const u16* __restrict__ Y1, const int* __restrict__ rowptr,
    const int* __restrict__ col, const u16* __restrict__ att,
    const u16* __restrict__ bias, u16* __restrict__ hout, int NN) {
    const int wid = blockIdx.x * 4 + (threadIdx.x >> 6);
    const int lane = threadIdx.x & 63;
    if (wid >= NN) return;
    const int n = wid;

    float xr[4], attv[4];
    {
        u16 tmp[4];
        *(uint2*)tmp = *(const uint2*)(Y1 + (size_t)n * JT1 + JH1 + lane * 4);
#pragma unroll
        for (int j = 0; j < 4; j++) xr[j] = b2f(tmp[j]);
        *(uint2*)tmp = *(const uint2*)(att + lane * 4);
#pragma unroll
        for (int j = 0; j < 4; j++) attv[j] = b2f(tmp[j]);
    }
    float acc[4] = {0.f, 0.f, 0.f, 0.f};
    float dsum = 0.f;
    const int beg = rowptr[n], end = rowptr[n + 1];
    for (int i = beg; i < end; i++) {
        int src = col[i];
        u16 tmp[4];
        *(uint2*)tmp = *(const uint2*)(Y1 + (size_t)src * JT1 + lane * 4);
        float xl[4], p = 0.f;
#pragma unroll
        for (int j = 0; j < 4; j++) {
            xl[j] = b2f(tmp[j]);
            float z = xl[j] + xr[j];
            z = (z > 0.f) ? z : 0.2f * z;
            p += z * attv[j];
        }
        p += __shfl_xor(p, 1); p += __shfl_xor(p, 2); p += __shfl_xor(p, 4);
        float e = __expf(p);
        dsum += e;
#pragma unroll
        for (int j = 0; j < 4; j++) acc[j] += e * xl[j];
    }
    float inv = 1.f / fmaxf(dsum, 1e-16f);
    u16 o[4];
#pragma unroll
    for (int j = 0; j < 4; j++) {
        float v = acc[j] * inv + b2f(bias[lane * 4 + j]);
        v = 0.5f * v * (1.f + erff(v * 0.70710678118654752f));
        o[j] = f2b(v);
    }
    *(uint2*)(hout + (size_t)n * JH1 + lane * 4) = *(uint2*)o;
}

// ---------------------------------------------------------------------------
// Layer-2 aggregate: one wave per dst node, two edges in flight (one per
// 32-lane half). Fused /denom + bias + dtype-flag store to d_out.
// ---------------------------------------------------------------------------
__global__ __launch_bounds__(256) void agg2(
    const u16* __restrict__ Y2, const int* __restrict__ rowptr,
    const int* __restrict__ col, const u16* __restrict__ att,
    const u16* __restrict__ bias, void* __restrict__ dout, int NN,
    const int* __restrict__ flag) {
    const int wid = blockIdx.x * 4 + (threadIdx.x >> 6);
    const int lane = threadIdx.x & 63;
    if (wid >= NN) return;
    const int n = wid, half = lane >> 5, c = lane & 31;

    float xr = b2f(Y2[(size_t)n * JT2 + JH2 + c]);
    float attv = b2f(att[c]);
    float acc = 0.f, dsum = 0.f;
    const int beg = rowptr[n], end = rowptr[n + 1];
    for (int i = beg + half; i < end; i += 2) {
        int src = col[i];
        float xl = b2f(Y2[(size_t)src * JT2 + c]);
        float z = xl + xr;
        z = (z > 0.f) ? z : 0.2f * z;
        float p = z * attv;
        p += __shfl_xor(p, 1); p += __shfl_xor(p, 2); p += __shfl_xor(p, 4);
        p += __shfl_xor(p, 8); p += __shfl_xor(p, 16);
        float e = __expf(p);
        dsum += e;
        acc += e * xl;
    }
    acc += __shfl_xor(acc, 32);
    dsum += __shfl_xor(dsum, 32);
    if (half == 0) {
        float v = acc / fmaxf(dsum, 1e-16f) + b2f(bias[c]);
        int idx = n * JH2 + c;
        if (*flag) ((u16*)dout)[idx] = f2b(v);
        else       ((float*)dout)[idx] = v;
    }
}

extern "C" void kernel_launch(void* const* d_in, const int* in_sizes, int n_in,
                              void* d_out, int out_size, void* d_ws, size_t ws_size,
                              hipStream_t stream) {
    const int NN = in_sizes[0] / F_IN;   // 50000
    const int EE = in_sizes[1] / 2;      // 800000
    const int EP = EE + NN;
    if (ws_size < WS_NEED) return;

    char* w = (char*)d_ws;
    u16*   Y1   = (u16*)(w + OFF_Y1);
    u16*   XC   = (u16*)(w + OFF_XC);
    u16*   hbuf = (u16*)(w + OFF_H);
    u16*   Y2   = (u16*)(w + OFF_Y2);
    int*   col  = (int*)(w + OFF_COL);
    int*   deg  = (int*)(w + OFF_DEG);
    int*   rowp = (int*)(w + OFF_ROW);
    int*   cur  = (int*)(w + OFF_CUR);
    u16*   Wc   = (u16*)(w + OFF_WC);
    int*   flag = (int*)(w + OFF_FLAG);

    const int* ei = (const int*)d_in[1];

    // 1) dtype probe + input canonicalization
    detect_dtype<<<1, 64, 0, stream>>>((const u16*)d_in[0], flag);
    cvt_bf16<<<(NN * F_IN + 255) / 256, 256, 0, stream>>>(d_in[0], XC, NN * F_IN, flag);
    {
        WcArgs a;
        int sizes[12] = {JH1 * F_IN, JH1, JH1 * F_IN, JH1, H1 * CH, JH1,
                         JH2 * JH1, JH2, JH2 * JH1, JH2, JH2, JH2};
        int c = 0;
        for (int s = 0; s < 12; s++) { a.src[s] = d_in[2 + s]; a.cum[s] = c; c += sizes[s]; }
        a.cum[12] = c;  // == W_TOTAL
        cvt_weights<<<(W_TOTAL + 255) / 256, 256, 0, stream>>>(a, Wc, W_TOTAL, flag);
    }

    // 2) CSR by dst (shared by both layers)
    hipMemsetAsync(deg, 0, (size_t)NN * 4, stream);
    build_deg<<<(EP + 255) / 256, 256, 0, stream>>>(ei, deg, EE, NN);
    scan_deg<<<1, 1024, 0, stream>>>(deg, rowp, cur, NN);
    scatter_edges<<<(EP + 255) / 256, 256, 0, stream>>>(ei, cur, col, EE, NN);

    // 3) layer 1
    {
        dim3 grid((NN + 31) / 32, JT1 / 64);
        gemm_node<F_IN><<<grid, 256, 0, stream>>>(XC, Wc + W_WL1, Wc + W_WR1,
                                                  Wc + W_BL1, Wc + W_BR1, Y1, NN, JH1);
    }
    agg1<<<(NN + 3) / 4, 256, 0, stream>>>(Y1, rowp, col, Wc + W_ATT1,
                                           Wc + W_BIAS1, hbuf, NN);

    // 4) layer 2
    {
        dim3 grid((NN + 31) / 32, JT2 / 64);
        gemm_node<JH1><<<grid, 256, 0, stream>>>(hbuf, Wc + W_WL2, Wc + W_WR2,
                                                 Wc + W_BL2, Wc + W_BR2, Y2, NN, JH2);
    }
    agg2<<<(NN + 3) / 4, 256, 0, stream>>>(Y2, rowp, col, Wc + W_ATT2,
                                           Wc + W_BIAS2, d_out, NN, flag);
}

// Round 3
// 409.252 us; speedup vs baseline: 3.6063x; 1.5456x over previous
//
#include <hip/hip_runtime.h>
#include <hip/hip_bf16.h>

// ---------------------------------------------------------------------------
// GATv2 x2 (PyG GATv2Conv semantics with self-loops), MI355X.
// R3: MFMA bf16 GEMMs (16x16x32, fragment-from-global, LDS-bounce C store),
// agg1 with 2 edges in flight per wave + 2-deep pipeline. CSR gather kept.
// ---------------------------------------------------------------------------

typedef unsigned short u16;
typedef short bf16x8 __attribute__((ext_vector_type(8)));
typedef float f32x4 __attribute__((ext_vector_type(4)));

#define F_IN   128
#define CH     32
#define H1     8
#define JT1    512   // 2 * H1*CH  (xl | xr concatenated)
#define JH1    256   // H1*CH
#define JT2    64    // 2 * CH
#define JH2    32

// ---- ws layout (bytes) ----------------------------------------------------
#define OFF_Y1     0UL
#define OFF_XC     52000000UL
#define OFF_H      52000000UL
#define OFF_Y2     78000000UL
#define OFF_COL    85000000UL
#define OFF_DEG    89000000UL
#define OFF_ROW    89400000UL
#define OFF_CUR    89800000UL
#define OFF_WC     90200000UL
#define OFF_FLAG   90600000UL
#define WS_NEED    91000000UL

// canonical weight offsets (elements within Wc), cumulative in input order
#define W_WL1   0
#define W_BL1   32768
#define W_WR1   33024
#define W_BR1   65792
#define W_ATT1  66048
#define W_BIAS1 66304
#define W_WL2   66560
#define W_BL2   74752
#define W_WR2   74784
#define W_BR2   82976
#define W_ATT2  83008
#define W_BIAS2 83040
#define W_TOTAL 83072

__device__ inline float b2f(u16 u) { return __uint_as_float(((unsigned)u) << 16); }
__device__ inline u16 f2b(float f) {
    unsigned u = __float_as_uint(f);
    unsigned r = (u + 0x7fffu + ((u >> 16) & 1u)) >> 16;
    return (u16)r;
}
// packed f32x2 -> bf16x2 (RNE), single instruction
__device__ inline unsigned cvtpk(float lo, float hi) {
    unsigned r;
    asm("v_cvt_pk_bf16_f32 %0, %1, %2" : "=v"(r) : "v"(lo), "v"(hi));
    return r;
}

// ---------------------------------------------------------------------------
// dtype probe + canonicalization (verified R1/R2)
// ---------------------------------------------------------------------------
__global__ void detect_dtype(const u16* __restrict__ x, int* __restrict__ flag) {
    int lane = threadIdx.x;
    int cnt = 0;
    for (int i = lane; i < 512; i += 64) {
        u16 u = x[i];
        int e = (u >> 7) & 0xff;
        cnt += (u == 0 || (e >= 100 && e <= 141)) ? 1 : 0;
    }
#pragma unroll
    for (int m = 32; m; m >>= 1) cnt += __shfl_xor(cnt, m);
    if (lane == 0) *flag = (cnt >= 440) ? 1 : 0;
}

__global__ void cvt_bf16(const void* __restrict__ src, u16* __restrict__ dst,
                         int n, const int* __restrict__ flag) {
    int i = blockIdx.x * 256 + threadIdx.x;
    if (i >= n) return;
    if (*flag) dst[i] = ((const u16*)src)[i];
    else       dst[i] = f2b(((const float*)src)[i]);
}

struct WcArgs { const void* src[12]; int cum[13]; };

__global__ void cvt_weights(WcArgs a, u16* __restrict__ dst, int total,
                            const int* __restrict__ flag) {
    int i = blockIdx.x * 256 + threadIdx.x;
    if (i >= total) return;
    int s = 0;
    while (i >= a.cum[s + 1]) s++;
    int rel = i - a.cum[s];
    if (*flag) dst[i] = ((const u16*)a.src[s])[rel];
    else       dst[i] = f2b(((const float*)a.src[s])[rel]);
}

// ---------------------------------------------------------------------------
// CSR build (verified R2)
// ---------------------------------------------------------------------------
__global__ void build_deg(const int* __restrict__ ei, int* __restrict__ deg,
                          int E_, int NP) {
    int e = blockIdx.x * 256 + threadIdx.x;
    if (e >= E_ + NP) return;
    int dst = (e < E_) ? ei[E_ + e] : e - E_;
    atomicAdd(deg + dst, 1);
}

__global__ __launch_bounds__(1024) void scan_deg(const int* __restrict__ deg,
                                                 int* __restrict__ rowptr,
                                                 int* __restrict__ cur, int NN) {
    int t = threadIdx.x;
    int chunk = (NN + 1023) >> 10;
    int beg = t * chunk, end = min(beg + chunk, NN);
    int s = 0;
    for (int i = beg; i < end; i++) s += deg[i];
    __shared__ int ps[1024];
    ps[t] = s; __syncthreads();
    for (int off = 1; off < 1024; off <<= 1) {
        int x = (t >= off) ? ps[t - off] : 0;
        __syncthreads();
        ps[t] += x;
        __syncthreads();
    }
    int run = t ? ps[t - 1] : 0;
    for (int i = beg; i < end; i++) { rowptr[i] = run; cur[i] = run; run += deg[i]; }
    if (t == 1023) rowptr[NN] = ps[1023];
}

__global__ void scatter_edges(const int* __restrict__ ei, int* __restrict__ cur,
                              int* __restrict__ col, int E_, int NP) {
    int e = blockIdx.x * 256 + threadIdx.x;
    if (e >= E_ + NP) return;
    int src, dst;
    if (e < E_) { src = ei[e]; dst = ei[E_ + e]; }
    else        { src = dst = e - E_; }
    int pos = atomicAdd(cur + dst, 1);
    col[pos] = src;
}

// ---------------------------------------------------------------------------
// MFMA GEMM: Y[m][2*JH] = X[m][K] @ [Wl;Wr][j][K]^T + [bl;br]
// Block = 4 waves; tile 128(M) x 64(N); wave = 32x64 via 2x4 16x16 frags.
// Fragments loaded directly from global (W-tile L1-hot). No barriers.
// C store: bias add -> per-wave LDS bounce -> cvt_pk -> 16B coalesced.
// Frag layouts (guide, ref-checked m91/m92): A/B lane l holds 8 contiguous
// bf16 at row/col = l&15, k = (l>>4)*8; D col = l&15, row = (l>>4)*4 + r.
// ---------------------------------------------------------------------------
template <int K>
__global__ __launch_bounds__(256) void gemm_mfma(
    const u16* __restrict__ X, const u16* __restrict__ Wl, const u16* __restrict__ Wr,
    const u16* __restrict__ bl, const u16* __restrict__ br,
    u16* __restrict__ Y, int M, int JH) {
    __shared__ float cs[4][32][68];      // per-wave private 32x64 (+4 pad)
    const int t = threadIdx.x, w = t >> 6, l = t & 63;
    const int bm0 = blockIdx.x * 128, bn0 = blockIdx.y * 64;
    const int JT = 2 * JH;
    const int lr = l & 15, lk = (l >> 4) * 8;

    const u16* ax[2];
#pragma unroll
    for (int mt = 0; mt < 2; mt++) {
        int row = bm0 + w * 32 + mt * 16 + lr;
        if (row >= M) row = M - 1;
        ax[mt] = X + (size_t)row * K + lk;
    }
    const u16* bx[4];
    float bv[4];
#pragma unroll
    for (int nt = 0; nt < 4; nt++) {
        int j = bn0 + nt * 16 + lr;
        const u16* wp = (j < JH) ? (Wl + (size_t)j * K) : (Wr + (size_t)(j - JH) * K);
        bx[nt] = wp + lk;
        bv[nt] = b2f(j < JH ? bl[j] : br[j - JH]);
    }

    f32x4 acc[2][4];
#pragma unroll
    for (int mt = 0; mt < 2; mt++)
#pragma unroll
        for (int nt = 0; nt < 4; nt++) acc[mt][nt] = (f32x4){0.f, 0.f, 0.f, 0.f};

#pragma unroll
    for (int k0 = 0; k0 < K; k0 += 32) {
        bf16x8 a[2], b[4];
#pragma unroll
        for (int mt = 0; mt < 2; mt++) a[mt] = *(const bf16x8*)(ax[mt] + k0);
#pragma unroll
        for (int nt = 0; nt < 4; nt++) b[nt] = *(const bf16x8*)(bx[nt] + k0);
#pragma unroll
        for (int mt = 0; mt < 2; mt++)
#pragma unroll
            for (int nt = 0; nt < 4; nt++)
                acc[mt][nt] = __builtin_amdgcn_mfma_f32_16x16x32_bf16(
                    a[mt], b[nt], acc[mt][nt], 0, 0, 0);
    }

    // scatter acc (+bias) into own LDS slice, then read rows back coalesced
#pragma unroll
    for (int mt = 0; mt < 2; mt++)
#pragma unroll
        for (int nt = 0; nt < 4; nt++)
#pragma unroll
            for (int r = 0; r < 4; r++)
                cs[w][mt * 16 + (l >> 4) * 4 + r][nt * 16 + lr] = acc[mt][nt][r] + bv[nt];

#pragma unroll
    for (int p = 0; p < 4; p++) {
        int rl = p * 8 + (l >> 3);
        int grow = bm0 + w * 32 + rl;
        if (grow < M) {
            const float* rp = &cs[w][rl][(l & 7) * 8];
            float4 v0 = *(const float4*)rp;
            float4 v1 = *(const float4*)(rp + 4);
            uint4 o;
            o.x = cvtpk(v0.x, v0.y); o.y = cvtpk(v0.z, v0.w);
            o.z = cvtpk(v1.x, v1.y); o.w = cvtpk(v1.z, v1.w);
            *(uint4*)(Y + (size_t)grow * JT + bn0 + (l & 7) * 8) = o;
        }
    }
}

// ---------------------------------------------------------------------------
// Layer-1 aggregate: one wave per dst node, TWO edges in flight (one per
// 32-lane half), 8 channels/lane, 4-lane logit reduce, 2-deep load pipeline.
// Fused /denom + bias + GELU.
// ---------------------------------------------------------------------------
__global__ __launch_bounds__(256) void agg1(
    const u16* __restrict__ Y1, const int* __restrict__ rowptr,
    const int* __restrict__ col, const u16* __restrict__ att,
    const u16* __restrict__ bias, u16* __restrict__ hout, int NN) {
    const int wid = blockIdx.x * 4 + (threadIdx.x >> 6);
    if (wid >= NN) return;
    const int lane = threadIdx.x & 63, half = lane >> 5, hl = lane & 31;
    const int n = wid;

    float xr[8], attv[8];
    {
        u16 u[8];
        *(uint4*)u = *(const uint4*)(Y1 + (size_t)n * JT1 + JH1 + hl * 8);
#pragma unroll
        for (int j = 0; j < 8; j++) xr[j] = b2f(u[j]);
        *(uint4*)u = *(const uint4*)(att + hl * 8);
#pragma unroll
        for (int j = 0; j < 8; j++) attv[j] = b2f(u[j]);
    }
    float acc[8] = {0.f, 0.f, 0.f, 0.f, 0.f, 0.f, 0.f, 0.f};
    float dsum = 0.f;

    auto edge = [&](uint4 raw) {
        u16 u[8];
        *(uint4*)u = raw;
        float xl[8], p = 0.f;
#pragma unroll
        for (int j = 0; j < 8; j++) {
            xl[j] = b2f(u[j]);
            float z = xl[j] + xr[j];
            z = (z > 0.f) ? z : 0.2f * z;
            p += z * attv[j];
        }
        p += __shfl_xor(p, 1); p += __shfl_xor(p, 2);
        float e = __expf(p);
        dsum += e;
#pragma unroll
        for (int j = 0; j < 8; j++) acc[j] += e * xl[j];
    };

    const int beg = rowptr[n], end = rowptr[n + 1];
    int i = beg + half;
    for (; i + 2 < end; i += 4) {
        int s0 = col[i], s1 = col[i + 2];
        uint4 r0 = *(const uint4*)(Y1 + (size_t)s0 * JT1 + hl * 8);
        uint4 r1 = *(const uint4*)(Y1 + (size_t)s1 * JT1 + hl * 8);
        edge(r0);
        edge(r1);
    }
    if (i < end) {
        uint4 r0 = *(const uint4*)(Y1 + (size_t)col[i] * JT1 + hl * 8);
        edge(r0);
    }

    dsum += __shfl_xor(dsum, 32);
#pragma unroll
    for (int j = 0; j < 8; j++) acc[j] += __shfl_xor(acc[j], 32);

    if (half == 0) {
        float inv = 1.f / fmaxf(dsum, 1e-16f);
        float v[8];
#pragma unroll
        for (int j = 0; j < 8; j++) {
            float x = acc[j] * inv + b2f(bias[hl * 8 + j]);
            v[j] = 0.5f * x * (1.f + erff(x * 0.70710678118654752f));
        }
        uint4 o;
        o.x = cvtpk(v[0], v[1]); o.y = cvtpk(v[2], v[3]);
        o.z = cvtpk(v[4], v[5]); o.w = cvtpk(v[6], v[7]);
        *(uint4*)(hout + (size_t)n * JH1 + hl * 8) = o;
    }
}

// ---------------------------------------------------------------------------
// Layer-2 aggregate (verified R2): one wave per dst node, two edges in flight.
// ---------------------------------------------------------------------------
__global__ __launch_bounds__(256) void agg2(
    const u16* __restrict__ Y2, const int* __restrict__ rowptr,
    const int* __restrict__ col, const u16* __restrict__ att,
    const u16* __restrict__ bias, void* __restrict__ dout, int NN,
    const int* __restrict__ flag) {
    const int wid = blockIdx.x * 4 + (threadIdx.x >> 6);
    const int lane = threadIdx.x & 63;
    if (wid >= NN) return;
    const int n = wid, half = lane >> 5, c = lane & 31;

    float xr = b2f(Y2[(size_t)n * JT2 + JH2 + c]);
    float attv = b2f(att[c]);
    float acc = 0.f, dsum = 0.f;
    const int beg = rowptr[n], end = rowptr[n + 1];
    for (int i = beg + half; i < end; i += 2) {
        int src = col[i];
        float xl = b2f(Y2[(size_t)src * JT2 + c]);
        float z = xl + xr;
        z = (z > 0.f) ? z : 0.2f * z;
        float p = z * attv;
        p += __shfl_xor(p, 1); p += __shfl_xor(p, 2); p += __shfl_xor(p, 4);
        p += __shfl_xor(p, 8); p += __shfl_xor(p, 16);
        float e = __expf(p);
        dsum += e;
        acc += e * xl;
    }
    acc += __shfl_xor(acc, 32);
    dsum += __shfl_xor(dsum, 32);
    if (half == 0) {
        float v = acc / fmaxf(dsum, 1e-16f) + b2f(bias[c]);
        int idx = n * JH2 + c;
        if (*flag) ((u16*)dout)[idx] = f2b(v);
        else       ((float*)dout)[idx] = v;
    }
}

extern "C" void kernel_launch(void* const* d_in, const int* in_sizes, int n_in,
                              void* d_out, int out_size, void* d_ws, size_t ws_size,
                              hipStream_t stream) {
    const int NN = in_sizes[0] / F_IN;   // 50000
    const int EE = in_sizes[1] / 2;      // 800000
    const int EP = EE + NN;
    if (ws_size < WS_NEED) return;

    char* w = (char*)d_ws;
    u16*   Y1   = (u16*)(w + OFF_Y1);
    u16*   XC   = (u16*)(w + OFF_XC);
    u16*   hbuf = (u16*)(w + OFF_H);
    u16*   Y2   = (u16*)(w + OFF_Y2);
    int*   col  = (int*)(w + OFF_COL);
    int*   deg  = (int*)(w + OFF_DEG);
    int*   rowp = (int*)(w + OFF_ROW);
    int*   cur  = (int*)(w + OFF_CUR);
    u16*   Wc   = (u16*)(w + OFF_WC);
    int*   flag = (int*)(w + OFF_FLAG);

    const int* ei = (const int*)d_in[1];

    // 1) dtype probe + input canonicalization
    detect_dtype<<<1, 64, 0, stream>>>((const u16*)d_in[0], flag);
    cvt_bf16<<<(NN * F_IN + 255) / 256, 256, 0, stream>>>(d_in[0], XC, NN * F_IN, flag);
    {
        WcArgs a;
        int sizes[12] = {JH1 * F_IN, JH1, JH1 * F_IN, JH1, H1 * CH, JH1,
                         JH2 * JH1, JH2, JH2 * JH1, JH2, JH2, JH2};
        int c = 0;
        for (int s = 0; s < 12; s++) { a.src[s] = d_in[2 + s]; a.cum[s] = c; c += sizes[s]; }
        a.cum[12] = c;
        cvt_weights<<<(W_TOTAL + 255) / 256, 256, 0, stream>>>(a, Wc, W_TOTAL, flag);
    }

    // 2) CSR by dst (shared by both layers)
    hipMemsetAsync(deg, 0, (size_t)NN * 4, stream);
    build_deg<<<(EP + 255) / 256, 256, 0, stream>>>(ei, deg, EE, NN);
    scan_deg<<<1, 1024, 0, stream>>>(deg, rowp, cur, NN);
    scatter_edges<<<(EP + 255) / 256, 256, 0, stream>>>(ei, cur, col, EE, NN);

    // 3) layer 1
    {
        dim3 grid((NN + 127) / 128, JT1 / 64);
        gemm_mfma<F_IN><<<grid, 256, 0, stream>>>(XC, Wc + W_WL1, Wc + W_WR1,
                                                  Wc + W_BL1, Wc + W_BR1, Y1, NN, JH1);
    }
    agg1<<<(NN + 3) / 4, 256, 0, stream>>>(Y1, rowp, col, Wc + W_ATT1,
                                           Wc + W_BIAS1, hbuf, NN);

    // 4) layer 2
    {
        dim3 grid((NN + 127) / 128, JT2 / 64);
        gemm_mfma<JH1><<<grid, 256, 0, stream>>>(hbuf, Wc + W_WL2, Wc + W_WR2,
                                                 Wc + W_BL2, Wc + W_BR2, Y2, NN, JH2);
    }
    agg2<<<(NN + 3) / 4, 256, 0, stream>>>(Y2, rowp, col, Wc + W_ATT2,
                                           Wc + W_BIAS2, d_out, NN, flag);
}

// Round 4
// 314.062 us; speedup vs baseline: 4.6993x; 1.3031x over previous
//
#include <hip/hip_runtime.h>
#include <hip/hip_bf16.h>

// ---------------------------------------------------------------------------
// GATv2 x2 (PyG GATv2Conv semantics with self-loops), MI355X.
// R4: multi-block CSR scan (was 110us single-block serial), 4-deep gather
// pipeline in agg1/agg2. MFMA GEMMs + CSR gather kept from R3.
// ---------------------------------------------------------------------------

typedef unsigned short u16;
typedef short bf16x8 __attribute__((ext_vector_type(8)));
typedef float f32x4 __attribute__((ext_vector_type(4)));

#define F_IN   128
#define CH     32
#define H1     8
#define JT1    512   // 2 * H1*CH  (xl | xr concatenated)
#define JH1    256   // H1*CH
#define JT2    64    // 2 * CH
#define JH2    32

// ---- ws layout (bytes) ----------------------------------------------------
#define OFF_Y1     0UL
#define OFF_XC     52000000UL
#define OFF_H      52000000UL
#define OFF_Y2     78000000UL
#define OFF_COL    85000000UL
#define OFF_DEG    89000000UL
#define OFF_ROW    89400000UL
#define OFF_CUR    89800000UL
#define OFF_WC     90200000UL
#define OFF_FLAG   90600000UL
#define OFF_BSUM   90700000UL
#define OFF_BOFF   90704096UL
#define WS_NEED    91000000UL

// canonical weight offsets (elements within Wc), cumulative in input order
#define W_WL1   0
#define W_BL1   32768
#define W_WR1   33024
#define W_BR1   65792
#define W_ATT1  66048
#define W_BIAS1 66304
#define W_WL2   66560
#define W_BL2   74752
#define W_WR2   74784
#define W_BR2   82976
#define W_ATT2  83008
#define W_BIAS2 83040
#define W_TOTAL 83072

__device__ inline float b2f(u16 u) { return __uint_as_float(((unsigned)u) << 16); }
__device__ inline u16 f2b(float f) {
    unsigned u = __float_as_uint(f);
    unsigned r = (u + 0x7fffu + ((u >> 16) & 1u)) >> 16;
    return (u16)r;
}
__device__ inline unsigned cvtpk(float lo, float hi) {
    unsigned r;
    asm("v_cvt_pk_bf16_f32 %0, %1, %2" : "=v"(r) : "v"(lo), "v"(hi));
    return r;
}

// ---------------------------------------------------------------------------
// dtype probe + canonicalization (verified R1-R3)
// ---------------------------------------------------------------------------
__global__ void detect_dtype(const u16* __restrict__ x, int* __restrict__ flag) {
    int lane = threadIdx.x;
    int cnt = 0;
    for (int i = lane; i < 512; i += 64) {
        u16 u = x[i];
        int e = (u >> 7) & 0xff;
        cnt += (u == 0 || (e >= 100 && e <= 141)) ? 1 : 0;
    }
#pragma unroll
    for (int m = 32; m; m >>= 1) cnt += __shfl_xor(cnt, m);
    if (lane == 0) *flag = (cnt >= 440) ? 1 : 0;
}

__global__ void cvt_bf16(const void* __restrict__ src, u16* __restrict__ dst,
                         int n, const int* __restrict__ flag) {
    int i = blockIdx.x * 256 + threadIdx.x;
    if (i >= n) return;
    if (*flag) dst[i] = ((const u16*)src)[i];
    else       dst[i] = f2b(((const float*)src)[i]);
}

struct WcArgs { const void* src[12]; int cum[13]; };

__global__ void cvt_weights(WcArgs a, u16* __restrict__ dst, int total,
                            const int* __restrict__ flag) {
    int i = blockIdx.x * 256 + threadIdx.x;
    if (i >= total) return;
    int s = 0;
    while (i >= a.cum[s + 1]) s++;
    int rel = i - a.cum[s];
    if (*flag) dst[i] = ((const u16*)a.src[s])[rel];
    else       dst[i] = f2b(((const float*)a.src[s])[rel]);
}

// ---------------------------------------------------------------------------
// CSR build: deg histogram -> 3-phase multi-block scan -> cursor scatter
// ---------------------------------------------------------------------------
__global__ void build_deg(const int* __restrict__ ei, int* __restrict__ deg,
                          int E_, int NP) {
    int e = blockIdx.x * 256 + threadIdx.x;
    if (e >= E_ + NP) return;
    int dst = (e < E_) ? ei[E_ + e] : e - E_;
    atomicAdd(deg + dst, 1);
}

// phase 1: per-block (1024-elem chunk) sums
__global__ __launch_bounds__(256) void scan_part(const int* __restrict__ deg,
                                                 int* __restrict__ bsum, int NN) {
    __shared__ int red[256];
    int b = blockIdx.x, t = threadIdx.x;
    int base = b * 1024 + t * 4;
    int s = 0;
#pragma unroll
    for (int j = 0; j < 4; j++) { int i = base + j; if (i < NN) s += deg[i]; }
    red[t] = s; __syncthreads();
    for (int off = 128; off; off >>= 1) {
        if (t < off) red[t] += red[t + off];
        __syncthreads();
    }
    if (t == 0) bsum[b] = red[0];
}

// phase 2: scan block sums (NB <= 256), write exclusive offsets + total
__global__ __launch_bounds__(256) void scan_block(const int* __restrict__ bsum,
                                                  int* __restrict__ boff,
                                                  int* __restrict__ total_out, int NB) {
    __shared__ int ps[256];
    int t = threadIdx.x;
    int v = (t < NB) ? bsum[t] : 0;
    ps[t] = v; __syncthreads();
    for (int off = 1; off < 256; off <<= 1) {
        int x = (t >= off) ? ps[t - off] : 0;
        __syncthreads();
        ps[t] += x;
        __syncthreads();
    }
    if (t < NB) boff[t] = ps[t] - v;
    if (t == 255) *total_out = ps[255];
}

// phase 3: per-block local scan + offset, write rowptr & cur
__global__ __launch_bounds__(256) void scan_final(const int* __restrict__ deg,
                                                  const int* __restrict__ boff,
                                                  int* __restrict__ rowptr,
                                                  int* __restrict__ cur, int NN) {
    __shared__ int ps[256];
    int b = blockIdx.x, t = threadIdx.x;
    int base = b * 1024 + t * 4;
    int v[4]; int s = 0;
#pragma unroll
    for (int j = 0; j < 4; j++) { int i = base + j; v[j] = (i < NN) ? deg[i] : 0; s += v[j]; }
    ps[t] = s; __syncthreads();
    for (int off = 1; off < 256; off <<= 1) {
        int x = (t >= off) ? ps[t - off] : 0;
        __syncthreads();
        ps[t] += x;
        __syncthreads();
    }
    int run = boff[b] + (t ? ps[t - 1] : 0);
#pragma unroll
    for (int j = 0; j < 4; j++) {
        int i = base + j;
        if (i < NN) { rowptr[i] = run; cur[i] = run; run += v[j]; }
    }
}

__global__ void scatter_edges(const int* __restrict__ ei, int* __restrict__ cur,
                              int* __restrict__ col, int E_, int NP) {
    int e = blockIdx.x * 256 + threadIdx.x;
    if (e >= E_ + NP) return;
    int src, dst;
    if (e < E_) { src = ei[e]; dst = ei[E_ + e]; }
    else        { src = dst = e - E_; }
    int pos = atomicAdd(cur + dst, 1);
    col[pos] = src;
}

// ---------------------------------------------------------------------------
// MFMA GEMM (verified R3): Y[m][2*JH] = X[m][K] @ [Wl;Wr]^T + [bl;br]
// ---------------------------------------------------------------------------
template <int K>
__global__ __launch_bounds__(256) void gemm_mfma(
    const u16* __restrict__ X, const u16* __restrict__ Wl, const u16* __restrict__ Wr,
    const u16* __restrict__ bl, const u16* __restrict__ br,
    u16* __restrict__ Y, int M, int JH) {
    __shared__ float cs[4][32][68];
    const int t = threadIdx.x, w = t >> 6, l = t & 63;
    const int bm0 = blockIdx.x * 128, bn0 = blockIdx.y * 64;
    const int JT = 2 * JH;
    const int lr = l & 15, lk = (l >> 4) * 8;

    const u16* ax[2];
#pragma unroll
    for (int mt = 0; mt < 2; mt++) {
        int row = bm0 + w * 32 + mt * 16 + lr;
        if (row >= M) row = M - 1;
        ax[mt] = X + (size_t)row * K + lk;
    }
    const u16* bx[4];
    float bv[4];
#pragma unroll
    for (int nt = 0; nt < 4; nt++) {
        int j = bn0 + nt * 16 + lr;
        const u16* wp = (j < JH) ? (Wl + (size_t)j * K) : (Wr + (size_t)(j - JH) * K);
        bx[nt] = wp + lk;
        bv[nt] = b2f(j < JH ? bl[j] : br[j - JH]);
    }

    f32x4 acc[2][4];
#pragma unroll
    for (int mt = 0; mt < 2; mt++)
#pragma unroll
        for (int nt = 0; nt < 4; nt++) acc[mt][nt] = (f32x4){0.f, 0.f, 0.f, 0.f};

#pragma unroll
    for (int k0 = 0; k0 < K; k0 += 32) {
        bf16x8 a[2], b[4];
#pragma unroll
        for (int mt = 0; mt < 2; mt++) a[mt] = *(const bf16x8*)(ax[mt] + k0);
#pragma unroll
        for (int nt = 0; nt < 4; nt++) b[nt] = *(const bf16x8*)(bx[nt] + k0);
#pragma unroll
        for (int mt = 0; mt < 2; mt++)
#pragma unroll
            for (int nt = 0; nt < 4; nt++)
                acc[mt][nt] = __builtin_amdgcn_mfma_f32_16x16x32_bf16(
                    a[mt], b[nt], acc[mt][nt], 0, 0, 0);
    }

#pragma unroll
    for (int mt = 0; mt < 2; mt++)
#pragma unroll
        for (int nt = 0; nt < 4; nt++)
#pragma unroll
            for (int r = 0; r < 4; r++)
                cs[w][mt * 16 + (l >> 4) * 4 + r][nt * 16 + lr] = acc[mt][nt][r] + bv[nt];

#pragma unroll
    for (int p = 0; p < 4; p++) {
        int rl = p * 8 + (l >> 3);
        int grow = bm0 + w * 32 + rl;
        if (grow < M) {
            const float* rp = &cs[w][rl][(l & 7) * 8];
            float4 v0 = *(const float4*)rp;
            float4 v1 = *(const float4*)(rp + 4);
            uint4 o;
            o.x = cvtpk(v0.x, v0.y); o.y = cvtpk(v0.z, v0.w);
            o.z = cvtpk(v1.x, v1.y); o.w = cvtpk(v1.z, v1.w);
            *(uint4*)(Y + (size_t)grow * JT + bn0 + (l & 7) * 8) = o;
        }
    }
}

// ---------------------------------------------------------------------------
// Layer-1 aggregate: one wave per dst node, 2 edges (one per 32-lane half),
// 4-deep load pipeline per half (8 gathers in flight per wave).
// ---------------------------------------------------------------------------
__global__ __launch_bounds__(256) void agg1(
    const u16* __restrict__ Y1, const int* __restrict__ rowptr,
    const int* __restrict__ col, const u16* __restrict__ att,
    const u16* __restrict__ bias, u16* __restrict__ hout, int NN) {
    const int wid = blockIdx.x * 4 + (threadIdx.x >> 6);
    if (wid >= NN) return;
    const int lane = threadIdx.x & 63, half = lane >> 5, hl = lane & 31;
    const int n = wid;

    float xr[8], attv[8];
    {
        u16 u[8];
        *(uint4*)u = *(const uint4*)(Y1 + (size_t)n * JT1 + JH1 + hl * 8);
#pragma unroll
        for (int j = 0; j < 8; j++) xr[j] = b2f(u[j]);
        *(uint4*)u = *(const uint4*)(att + hl * 8);
#pragma unroll
        for (int j = 0; j < 8; j++) attv[j] = b2f(u[j]);
    }
    float acc[8] = {0.f, 0.f, 0.f, 0.f, 0.f, 0.f, 0.f, 0.f};
    float dsum = 0.f;

    auto edge = [&](uint4 raw) {
        u16 u[8];
        *(uint4*)u = raw;
        float xl[8], p = 0.f;
#pragma unroll
        for (int j = 0; j < 8; j++) {
            xl[j] = b2f(u[j]);
            float z = xl[j] + xr[j];
            z = (z > 0.f) ? z : 0.2f * z;
            p += z * attv[j];
        }
        p += __shfl_xor(p, 1); p += __shfl_xor(p, 2);
        float e = __expf(p);
        dsum += e;
#pragma unroll
        for (int j = 0; j < 8; j++) acc[j] += e * xl[j];
    };

    const int beg = rowptr[n], end = rowptr[n + 1];
    int i = beg + half;
    for (; i + 6 < end; i += 8) {
        int s0 = col[i], s1 = col[i + 2], s2 = col[i + 4], s3 = col[i + 6];
        uint4 r0 = *(const uint4*)(Y1 + (size_t)s0 * JT1 + hl * 8);
        uint4 r1 = *(const uint4*)(Y1 + (size_t)s1 * JT1 + hl * 8);
        uint4 r2 = *(const uint4*)(Y1 + (size_t)s2 * JT1 + hl * 8);
        uint4 r3 = *(const uint4*)(Y1 + (size_t)s3 * JT1 + hl * 8);
        edge(r0); edge(r1); edge(r2); edge(r3);
    }
    for (; i < end; i += 2) {
        uint4 r0 = *(const uint4*)(Y1 + (size_t)col[i] * JT1 + hl * 8);
        edge(r0);
    }

    dsum += __shfl_xor(dsum, 32);
#pragma unroll
    for (int j = 0; j < 8; j++) acc[j] += __shfl_xor(acc[j], 32);

    if (half == 0) {
        float inv = 1.f / fmaxf(dsum, 1e-16f);
        float v[8];
#pragma unroll
        for (int j = 0; j < 8; j++) {
            float x = acc[j] * inv + b2f(bias[hl * 8 + j]);
            v[j] = 0.5f * x * (1.f + erff(x * 0.70710678118654752f));
        }
        uint4 o;
        o.x = cvtpk(v[0], v[1]); o.y = cvtpk(v[2], v[3]);
        o.z = cvtpk(v[4], v[5]); o.w = cvtpk(v[6], v[7]);
        *(uint4*)(hout + (size_t)n * JH1 + hl * 8) = o;
    }
}

// ---------------------------------------------------------------------------
// Layer-2 aggregate: one wave per dst node, 2 edges per step, 4-deep pipeline.
// ---------------------------------------------------------------------------
__global__ __launch_bounds__(256) void agg2(
    const u16* __restrict__ Y2, const int* __restrict__ rowptr,
    const int* __restrict__ col, const u16* __restrict__ att,
    const u16* __restrict__ bias, void* __restrict__ dout, int NN,
    const int* __restrict__ flag) {
    const int wid = blockIdx.x * 4 + (threadIdx.x >> 6);
    const int lane = threadIdx.x & 63;
    if (wid >= NN) return;
    const int n = wid, half = lane >> 5, c = lane & 31;

    float xr = b2f(Y2[(size_t)n * JT2 + JH2 + c]);
    float attv = b2f(att[c]);
    float acc = 0.f, dsum = 0.f;

    auto edge = [&](float xl) {
        float z = xl + xr;
        z = (z > 0.f) ? z : 0.2f * z;
        float p = z * attv;
        p += __shfl_xor(p, 1); p += __shfl_xor(p, 2); p += __shfl_xor(p, 4);
        p += __shfl_xor(p, 8); p += __shfl_xor(p, 16);
        float e = __expf(p);
        dsum += e;
        acc += e * xl;
    };

    const int beg = rowptr[n], end = rowptr[n + 1];
    int i = beg + half;
    for (; i + 6 < end; i += 8) {
        int s0 = col[i], s1 = col[i + 2], s2 = col[i + 4], s3 = col[i + 6];
        float x0 = b2f(Y2[(size_t)s0 * JT2 + c]);
        float x1 = b2f(Y2[(size_t)s1 * JT2 + c]);
        float x2 = b2f(Y2[(size_t)s2 * JT2 + c]);
        float x3 = b2f(Y2[(size_t)s3 * JT2 + c]);
        edge(x0); edge(x1); edge(x2); edge(x3);
    }
    for (; i < end; i += 2) {
        edge(b2f(Y2[(size_t)col[i] * JT2 + c]));
    }

    acc += __shfl_xor(acc, 32);
    dsum += __shfl_xor(dsum, 32);
    if (half == 0) {
        float v = acc / fmaxf(dsum, 1e-16f) + b2f(bias[c]);
        int idx = n * JH2 + c;
        if (*flag) ((u16*)dout)[idx] = f2b(v);
        else       ((float*)dout)[idx] = v;
    }
}

extern "C" void kernel_launch(void* const* d_in, const int* in_sizes, int n_in,
                              void* d_out, int out_size, void* d_ws, size_t ws_size,
                              hipStream_t stream) {
    const int NN = in_sizes[0] / F_IN;   // 50000
    const int EE = in_sizes[1] / 2;      // 800000
    const int EP = EE + NN;
    if (ws_size < WS_NEED) return;

    char* w = (char*)d_ws;
    u16*   Y1   = (u16*)(w + OFF_Y1);
    u16*   XC   = (u16*)(w + OFF_XC);
    u16*   hbuf = (u16*)(w + OFF_H);
    u16*   Y2   = (u16*)(w + OFF_Y2);
    int*   col  = (int*)(w + OFF_COL);
    int*   deg  = (int*)(w + OFF_DEG);
    int*   rowp = (int*)(w + OFF_ROW);
    int*   cur  = (int*)(w + OFF_CUR);
    u16*   Wc   = (u16*)(w + OFF_WC);
    int*   flag = (int*)(w + OFF_FLAG);
    int*   bsum = (int*)(w + OFF_BSUM);
    int*   boff = (int*)(w + OFF_BOFF);

    const int* ei = (const int*)d_in[1];

    // 1) dtype probe + input canonicalization
    detect_dtype<<<1, 64, 0, stream>>>((const u16*)d_in[0], flag);
    cvt_bf16<<<(NN * F_IN + 255) / 256, 256, 0, stream>>>(d_in[0], XC, NN * F_IN, flag);
    {
        WcArgs a;
        int sizes[12] = {JH1 * F_IN, JH1, JH1 * F_IN, JH1, H1 * CH, JH1,
                         JH2 * JH1, JH2, JH2 * JH1, JH2, JH2, JH2};
        int c = 0;
        for (int s = 0; s < 12; s++) { a.src[s] = d_in[2 + s]; a.cum[s] = c; c += sizes[s]; }
        a.cum[12] = c;
        cvt_weights<<<(W_TOTAL + 255) / 256, 256, 0, stream>>>(a, Wc, W_TOTAL, flag);
    }

    // 2) CSR by dst (shared by both layers); NB blocks of 1024 elems
    const int NB = (NN + 1023) / 1024;   // 49 for NN=50000 (<=256 supported)
    hipMemsetAsync(deg, 0, (size_t)NN * 4, stream);
    build_deg<<<(EP + 255) / 256, 256, 0, stream>>>(ei, deg, EE, NN);
    scan_part<<<NB, 256, 0, stream>>>(deg, bsum, NN);
    scan_block<<<1, 256, 0, stream>>>(bsum, boff, rowp + NN, NB);
    scan_final<<<NB, 256, 0, stream>>>(deg, boff, rowp, cur, NN);
    scatter_edges<<<(EP + 255) / 256, 256, 0, stream>>>(ei, cur, col, EE, NN);

    // 3) layer 1
    {
        dim3 grid((NN + 127) / 128, JT1 / 64);
        gemm_mfma<F_IN><<<grid, 256, 0, stream>>>(XC, Wc + W_WL1, Wc + W_WR1,
                                                  Wc + W_BL1, Wc + W_BR1, Y1, NN, JH1);
    }
    agg1<<<(NN + 3) / 4, 256, 0, stream>>>(Y1, rowp, col, Wc + W_ATT1,
                                           Wc + W_BIAS1, hbuf, NN);

    // 4) layer 2
    {
        dim3 grid((NN + 127) / 128, JT2 / 64);
        gemm_mfma<JH1><<<grid, 256, 0, stream>>>(hbuf, Wc + W_WL2, Wc + W_WR2,
                                                 Wc + W_BL2, Wc + W_BR2, Y2, NN, JH2);
    }
    agg2<<<(NN + 3) / 4, 256, 0, stream>>>(Y2, rowp, col, Wc + W_ATT2,
                                           Wc + W_BIAS2, d_out, NN, flag);
}

// Round 5
// 289.070 us; speedup vs baseline: 5.1056x; 1.0865x over previous
//
#include <hip/hip_runtime.h>
#include <hip/hip_bf16.h>

// ---------------------------------------------------------------------------
// GATv2 x2 (PyG GATv2Conv semantics with self-loops), MI355X.
// R5: agg1 packed-fp32 math (v_pk_add/v_pk_fma, leaky folded into att as
// 0.6att/0.4att) + 8-deep gather pipeline in agg1/agg2.
// MFMA GEMMs + multi-block CSR scan kept from R4.
// ---------------------------------------------------------------------------

typedef unsigned short u16;
typedef short bf16x8 __attribute__((ext_vector_type(8)));
typedef float f32x4 __attribute__((ext_vector_type(4)));
typedef float f32x2 __attribute__((ext_vector_type(2)));

#define F_IN   128
#define CH     32
#define H1     8
#define JT1    512   // 2 * H1*CH  (xl | xr concatenated)
#define JH1    256   // H1*CH
#define JT2    64    // 2 * CH
#define JH2    32

// ---- ws layout (bytes) ----------------------------------------------------
#define OFF_Y1     0UL
#define OFF_XC     52000000UL
#define OFF_H      52000000UL
#define OFF_Y2     78000000UL
#define OFF_COL    85000000UL
#define OFF_DEG    89000000UL
#define OFF_ROW    89400000UL
#define OFF_CUR    89800000UL
#define OFF_WC     90200000UL
#define OFF_FLAG   90600000UL
#define OFF_BSUM   90700000UL
#define OFF_BOFF   90704096UL
#define WS_NEED    91000000UL

// canonical weight offsets (elements within Wc), cumulative in input order
#define W_WL1   0
#define W_BL1   32768
#define W_WR1   33024
#define W_BR1   65792
#define W_ATT1  66048
#define W_BIAS1 66304
#define W_WL2   66560
#define W_BL2   74752
#define W_WR2   74784
#define W_BR2   82976
#define W_ATT2  83008
#define W_BIAS2 83040
#define W_TOTAL 83072

__device__ inline float b2f(u16 u) { return __uint_as_float(((unsigned)u) << 16); }
__device__ inline u16 f2b(float f) {
    unsigned u = __float_as_uint(f);
    unsigned r = (u + 0x7fffu + ((u >> 16) & 1u)) >> 16;
    return (u16)r;
}
__device__ inline unsigned cvtpk(float lo, float hi) {
    unsigned r;
    asm("v_cvt_pk_bf16_f32 %0, %1, %2" : "=v"(r) : "v"(lo), "v"(hi));
    return r;
}
// VOP3P packed fp32 (gfx90a+): default op_sel gives elementwise lo/hi
__device__ inline f32x2 pk_add(f32x2 a, f32x2 b) {
    f32x2 d;
    asm("v_pk_add_f32 %0, %1, %2" : "=v"(d) : "v"(a), "v"(b));
    return d;
}
__device__ inline f32x2 pk_fma(f32x2 a, f32x2 b, f32x2 c) {
    f32x2 d;
    asm("v_pk_fma_f32 %0, %1, %2, %3" : "=v"(d) : "v"(a), "v"(b), "v"(c));
    return d;
}
// unpack 2 bf16 (one dword) -> f32 pair (lo = even channel)
__device__ inline f32x2 unpk(unsigned u) {
    f32x2 d;
    d.x = __uint_as_float(u << 16);
    d.y = __uint_as_float(u & 0xffff0000u);
    return d;
}
__device__ inline f32x2 pabs(f32x2 z) {
    f32x2 d;
    d.x = __uint_as_float(__float_as_uint(z.x) & 0x7fffffffu);
    d.y = __uint_as_float(__float_as_uint(z.y) & 0x7fffffffu);
    return d;
}

// ---------------------------------------------------------------------------
// dtype probe + canonicalization (verified R1-R4)
// ---------------------------------------------------------------------------
__global__ void detect_dtype(const u16* __restrict__ x, int* __restrict__ flag) {
    int lane = threadIdx.x;
    int cnt = 0;
    for (int i = lane; i < 512; i += 64) {
        u16 u = x[i];
        int e = (u >> 7) & 0xff;
        cnt += (u == 0 || (e >= 100 && e <= 141)) ? 1 : 0;
    }
#pragma unroll
    for (int m = 32; m; m >>= 1) cnt += __shfl_xor(cnt, m);
    if (lane == 0) *flag = (cnt >= 440) ? 1 : 0;
}

__global__ void cvt_bf16(const void* __restrict__ src, u16* __restrict__ dst,
                         int n, const int* __restrict__ flag) {
    int i = blockIdx.x * 256 + threadIdx.x;
    if (i >= n) return;
    if (*flag) dst[i] = ((const u16*)src)[i];
    else       dst[i] = f2b(((const float*)src)[i]);
}

struct WcArgs { const void* src[12]; int cum[13]; };

__global__ void cvt_weights(WcArgs a, u16* __restrict__ dst, int total,
                            const int* __restrict__ flag) {
    int i = blockIdx.x * 256 + threadIdx.x;
    if (i >= total) return;
    int s = 0;
    while (i >= a.cum[s + 1]) s++;
    int rel = i - a.cum[s];
    if (*flag) dst[i] = ((const u16*)a.src[s])[rel];
    else       dst[i] = f2b(((const float*)a.src[s])[rel]);
}

// ---------------------------------------------------------------------------
// CSR build (verified R4): histogram -> 3-phase scan -> cursor scatter
// ---------------------------------------------------------------------------
__global__ void build_deg(const int* __restrict__ ei, int* __restrict__ deg,
                          int E_, int NP) {
    int e = blockIdx.x * 256 + threadIdx.x;
    if (e >= E_ + NP) return;
    int dst = (e < E_) ? ei[E_ + e] : e - E_;
    atomicAdd(deg + dst, 1);
}

__global__ __launch_bounds__(256) void scan_part(const int* __restrict__ deg,
                                                 int* __restrict__ bsum, int NN) {
    __shared__ int red[256];
    int b = blockIdx.x, t = threadIdx.x;
    int base = b * 1024 + t * 4;
    int s = 0;
#pragma unroll
    for (int j = 0; j < 4; j++) { int i = base + j; if (i < NN) s += deg[i]; }
    red[t] = s; __syncthreads();
    for (int off = 128; off; off >>= 1) {
        if (t < off) red[t] += red[t + off];
        __syncthreads();
    }
    if (t == 0) bsum[b] = red[0];
}

__global__ __launch_bounds__(256) void scan_block(const int* __restrict__ bsum,
                                                  int* __restrict__ boff,
                                                  int* __restrict__ total_out, int NB) {
    __shared__ int ps[256];
    int t = threadIdx.x;
    int v = (t < NB) ? bsum[t] : 0;
    ps[t] = v; __syncthreads();
    for (int off = 1; off < 256; off <<= 1) {
        int x = (t >= off) ? ps[t - off] : 0;
        __syncthreads();
        ps[t] += x;
        __syncthreads();
    }
    if (t < NB) boff[t] = ps[t] - v;
    if (t == 255) *total_out = ps[255];
}

__global__ __launch_bounds__(256) void scan_final(const int* __restrict__ deg,
                                                  const int* __restrict__ boff,
                                                  int* __restrict__ rowptr,
                                                  int* __restrict__ cur, int NN) {
    __shared__ int ps[256];
    int b = blockIdx.x, t = threadIdx.x;
    int base = b * 1024 + t * 4;
    int v[4]; int s = 0;
#pragma unroll
    for (int j = 0; j < 4; j++) { int i = base + j; v[j] = (i < NN) ? deg[i] : 0; s += v[j]; }
    ps[t] = s; __syncthreads();
    for (int off = 1; off < 256; off <<= 1) {
        int x = (t >= off) ? ps[t - off] : 0;
        __syncthreads();
        ps[t] += x;
        __syncthreads();
    }
    int run = boff[b] + (t ? ps[t - 1] : 0);
#pragma unroll
    for (int j = 0; j < 4; j++) {
        int i = base + j;
        if (i < NN) { rowptr[i] = run; cur[i] = run; run += v[j]; }
    }
}

__global__ void scatter_edges(const int* __restrict__ ei, int* __restrict__ cur,
                              int* __restrict__ col, int E_, int NP) {
    int e = blockIdx.x * 256 + threadIdx.x;
    if (e >= E_ + NP) return;
    int src, dst;
    if (e < E_) { src = ei[e]; dst = ei[E_ + e]; }
    else        { src = dst = e - E_; }
    int pos = atomicAdd(cur + dst, 1);
    col[pos] = src;
}

// ---------------------------------------------------------------------------
// MFMA GEMM (verified R3): Y[m][2*JH] = X[m][K] @ [Wl;Wr]^T + [bl;br]
// ---------------------------------------------------------------------------
template <int K>
__global__ __launch_bounds__(256) void gemm_mfma(
    const u16* __restrict__ X, const u16* __restrict__ Wl, const u16* __restrict__ Wr,
    const u16* __restrict__ bl, const u16* __restrict__ br,
    u16* __restrict__ Y, int M, int JH) {
    __shared__ float cs[4][32][68];
    const int t = threadIdx.x, w = t >> 6, l = t & 63;
    const int bm0 = blockIdx.x * 128, bn0 = blockIdx.y * 64;
    const int JT = 2 * JH;
    const int lr = l & 15, lk = (l >> 4) * 8;

    const u16* ax[2];
#pragma unroll
    for (int mt = 0; mt < 2; mt++) {
        int row = bm0 + w * 32 + mt * 16 + lr;
        if (row >= M) row = M - 1;
        ax[mt] = X + (size_t)row * K + lk;
    }
    const u16* bx[4];
    float bv[4];
#pragma unroll
    for (int nt = 0; nt < 4; nt++) {
        int j = bn0 + nt * 16 + lr;
        const u16* wp = (j < JH) ? (Wl + (size_t)j * K) : (Wr + (size_t)(j - JH) * K);
        bx[nt] = wp + lk;
        bv[nt] = b2f(j < JH ? bl[j] : br[j - JH]);
    }

    f32x4 acc[2][4];
#pragma unroll
    for (int mt = 0; mt < 2; mt++)
#pragma unroll
        for (int nt = 0; nt < 4; nt++) acc[mt][nt] = (f32x4){0.f, 0.f, 0.f, 0.f};

#pragma unroll
    for (int k0 = 0; k0 < K; k0 += 32) {
        bf16x8 a[2], b[4];
#pragma unroll
        for (int mt = 0; mt < 2; mt++) a[mt] = *(const bf16x8*)(ax[mt] + k0);
#pragma unroll
        for (int nt = 0; nt < 4; nt++) b[nt] = *(const bf16x8*)(bx[nt] + k0);
#pragma unroll
        for (int mt = 0; mt < 2; mt++)
#pragma unroll
            for (int nt = 0; nt < 4; nt++)
                acc[mt][nt] = __builtin_amdgcn_mfma_f32_16x16x32_bf16(
                    a[mt], b[nt], acc[mt][nt], 0, 0, 0);
    }

#pragma unroll
    for (int mt = 0; mt < 2; mt++)
#pragma unroll
        for (int nt = 0; nt < 4; nt++)
#pragma unroll
            for (int r = 0; r < 4; r++)
                cs[w][mt * 16 + (l >> 4) * 4 + r][nt * 16 + lr] = acc[mt][nt][r] + bv[nt];

#pragma unroll
    for (int p = 0; p < 4; p++) {
        int rl = p * 8 + (l >> 3);
        int grow = bm0 + w * 32 + rl;
        if (grow < M) {
            const float* rp = &cs[w][rl][(l & 7) * 8];
            float4 v0 = *(const float4*)rp;
            float4 v1 = *(const float4*)(rp + 4);
            uint4 o;
            o.x = cvtpk(v0.x, v0.y); o.y = cvtpk(v0.z, v0.w);
            o.z = cvtpk(v1.x, v1.y); o.w = cvtpk(v1.z, v1.w);
            *(uint4*)(Y + (size_t)grow * JT + bn0 + (l & 7) * 8) = o;
        }
    }
}

// ---------------------------------------------------------------------------
// Layer-1 aggregate: one wave per dst node, 2 edges (one per 32-lane half),
// packed-fp32 math: p = sum z*(0.6att) + |z|*(0.4att)  (== leaky(z)*att),
// acc via pk_fma. 8/4/1-tier gather pipeline.
// ---------------------------------------------------------------------------
__global__ __launch_bounds__(256, 4) void agg1(
    const u16* __restrict__ Y1, const int* __restrict__ rowptr,
    const int* __restrict__ col, const u16* __restrict__ att,
    const u16* __restrict__ bias, u16* __restrict__ hout, int NN) {
    const int wid = blockIdx.x * 4 + (threadIdx.x >> 6);
    if (wid >= NN) return;
    const int lane = threadIdx.x & 63, half = lane >> 5, hl = lane & 31;
    const int n = wid;

    f32x2 xr2[4], a06[4], a04[4];
    {
        uint4 rx = *(const uint4*)(Y1 + (size_t)n * JT1 + JH1 + hl * 8);
        uint4 ra = *(const uint4*)(att + hl * 8);
        unsigned ux[4] = {rx.x, rx.y, rx.z, rx.w};
        unsigned ua[4] = {ra.x, ra.y, ra.z, ra.w};
#pragma unroll
        for (int p = 0; p < 4; p++) {
            xr2[p] = unpk(ux[p]);
            f32x2 a = unpk(ua[p]);
            a06[p].x = 0.6f * a.x; a06[p].y = 0.6f * a.y;
            a04[p].x = 0.4f * a.x; a04[p].y = 0.4f * a.y;
        }
    }
    f32x2 acc2[4] = {{0.f,0.f},{0.f,0.f},{0.f,0.f},{0.f,0.f}};
    float dsum = 0.f;

    auto edge = [&](uint4 raw) {
        unsigned uw[4] = {raw.x, raw.y, raw.z, raw.w};
        f32x2 xl2[4];
        f32x2 p2 = {0.f, 0.f};
#pragma unroll
        for (int p = 0; p < 4; p++) {
            xl2[p] = unpk(uw[p]);
            f32x2 z = pk_add(xl2[p], xr2[p]);
            p2 = pk_fma(z, a06[p], p2);
            p2 = pk_fma(pabs(z), a04[p], p2);
        }
        float pl = p2.x + p2.y;
        pl += __shfl_xor(pl, 1); pl += __shfl_xor(pl, 2);
        float e = __expf(pl);
        dsum += e;
        f32x2 e2; e2.x = e; e2.y = e;
#pragma unroll
        for (int p = 0; p < 4; p++) acc2[p] = pk_fma(e2, xl2[p], acc2[p]);
    };

    const int beg = rowptr[n], end = rowptr[n + 1];
    int i = beg + half;
    for (; i + 14 < end; i += 16) {
        int s[8];
#pragma unroll
        for (int k = 0; k < 8; k++) s[k] = col[i + 2 * k];
        uint4 r[8];
#pragma unroll
        for (int k = 0; k < 8; k++) r[k] = *(const uint4*)(Y1 + (size_t)s[k] * JT1 + hl * 8);
#pragma unroll
        for (int k = 0; k < 8; k++) edge(r[k]);
    }
    for (; i + 6 < end; i += 8) {
        int s0 = col[i], s1 = col[i + 2], s2 = col[i + 4], s3 = col[i + 6];
        uint4 r0 = *(const uint4*)(Y1 + (size_t)s0 * JT1 + hl * 8);
        uint4 r1 = *(const uint4*)(Y1 + (size_t)s1 * JT1 + hl * 8);
        uint4 r2 = *(const uint4*)(Y1 + (size_t)s2 * JT1 + hl * 8);
        uint4 r3 = *(const uint4*)(Y1 + (size_t)s3 * JT1 + hl * 8);
        edge(r0); edge(r1); edge(r2); edge(r3);
    }
    for (; i < end; i += 2) {
        uint4 r0 = *(const uint4*)(Y1 + (size_t)col[i] * JT1 + hl * 8);
        edge(r0);
    }

    dsum += __shfl_xor(dsum, 32);
#pragma unroll
    for (int p = 0; p < 4; p++) {
        acc2[p].x += __shfl_xor(acc2[p].x, 32);
        acc2[p].y += __shfl_xor(acc2[p].y, 32);
    }

    if (half == 0) {
        float inv = 1.f / fmaxf(dsum, 1e-16f);
        u16 bu[8];
        *(uint4*)bu = *(const uint4*)(bias + hl * 8);
        float v[8];
#pragma unroll
        for (int p = 0; p < 4; p++) {
            float x0 = acc2[p].x * inv + b2f(bu[2 * p]);
            float x1 = acc2[p].y * inv + b2f(bu[2 * p + 1]);
            v[2 * p]     = 0.5f * x0 * (1.f + erff(x0 * 0.70710678118654752f));
            v[2 * p + 1] = 0.5f * x1 * (1.f + erff(x1 * 0.70710678118654752f));
        }
        uint4 o;
        o.x = cvtpk(v[0], v[1]); o.y = cvtpk(v[2], v[3]);
        o.z = cvtpk(v[4], v[5]); o.w = cvtpk(v[6], v[7]);
        *(uint4*)(hout + (size_t)n * JH1 + hl * 8) = o;
    }
}

// ---------------------------------------------------------------------------
// Layer-2 aggregate: one wave per dst node, 2 edges per step, 8/4/1 pipeline.
// ---------------------------------------------------------------------------
__global__ __launch_bounds__(256) void agg2(
    const u16* __restrict__ Y2, const int* __restrict__ rowptr,
    const int* __restrict__ col, const u16* __restrict__ att,
    const u16* __restrict__ bias, void* __restrict__ dout, int NN,
    const int* __restrict__ flag) {
    const int wid = blockIdx.x * 4 + (threadIdx.x >> 6);
    const int lane = threadIdx.x & 63;
    if (wid >= NN) return;
    const int n = wid, half = lane >> 5, c = lane & 31;

    float xr = b2f(Y2[(size_t)n * JT2 + JH2 + c]);
    float attv = b2f(att[c]);
    float acc = 0.f, dsum = 0.f;

    auto edge = [&](float xl) {
        float z = xl + xr;
        z = fmaf(0.4f, fabsf(z), 0.6f * z);   // leaky 0.2
        float p = z * attv;
        p += __shfl_xor(p, 1); p += __shfl_xor(p, 2); p += __shfl_xor(p, 4);
        p += __shfl_xor(p, 8); p += __shfl_xor(p, 16);
        float e = __expf(p);
        dsum += e;
        acc += e * xl;
    };

    const int beg = rowptr[n], end = rowptr[n + 1];
    int i = beg + half;
    for (; i + 14 < end; i += 16) {
        int s[8];
#pragma unroll
        for (int k = 0; k < 8; k++) s[k] = col[i + 2 * k];
        float x[8];
#pragma unroll
        for (int k = 0; k < 8; k++) x[k] = b2f(Y2[(size_t)s[k] * JT2 + c]);
#pragma unroll
        for (int k = 0; k < 8; k++) edge(x[k]);
    }
    for (; i + 6 < end; i += 8) {
        int s0 = col[i], s1 = col[i + 2], s2 = col[i + 4], s3 = col[i + 6];
        float x0 = b2f(Y2[(size_t)s0 * JT2 + c]);
        float x1 = b2f(Y2[(size_t)s1 * JT2 + c]);
        float x2 = b2f(Y2[(size_t)s2 * JT2 + c]);
        float x3 = b2f(Y2[(size_t)s3 * JT2 + c]);
        edge(x0); edge(x1); edge(x2); edge(x3);
    }
    for (; i < end; i += 2) {
        edge(b2f(Y2[(size_t)col[i] * JT2 + c]));
    }

    acc += __shfl_xor(acc, 32);
    dsum += __shfl_xor(dsum, 32);
    if (half == 0) {
        float v = acc / fmaxf(dsum, 1e-16f) + b2f(bias[c]);
        int idx = n * JH2 + c;
        if (*flag) ((u16*)dout)[idx] = f2b(v);
        else       ((float*)dout)[idx] = v;
    }
}

extern "C" void kernel_launch(void* const* d_in, const int* in_sizes, int n_in,
                              void* d_out, int out_size, void* d_ws, size_t ws_size,
                              hipStream_t stream) {
    const int NN = in_sizes[0] / F_IN;   // 50000
    const int EE = in_sizes[1] / 2;      // 800000
    const int EP = EE + NN;
    if (ws_size < WS_NEED) return;

    char* w = (char*)d_ws;
    u16*   Y1   = (u16*)(w + OFF_Y1);
    u16*   XC   = (u16*)(w + OFF_XC);
    u16*   hbuf = (u16*)(w + OFF_H);
    u16*   Y2   = (u16*)(w + OFF_Y2);
    int*   col  = (int*)(w + OFF_COL);
    int*   deg  = (int*)(w + OFF_DEG);
    int*   rowp = (int*)(w + OFF_ROW);
    int*   cur  = (int*)(w + OFF_CUR);
    u16*   Wc   = (u16*)(w + OFF_WC);
    int*   flag = (int*)(w + OFF_FLAG);
    int*   bsum = (int*)(w + OFF_BSUM);
    int*   boff = (int*)(w + OFF_BOFF);

    const int* ei = (const int*)d_in[1];

    // 1) dtype probe + input canonicalization
    detect_dtype<<<1, 64, 0, stream>>>((const u16*)d_in[0], flag);
    cvt_bf16<<<(NN * F_IN + 255) / 256, 256, 0, stream>>>(d_in[0], XC, NN * F_IN, flag);
    {
        WcArgs a;
        int sizes[12] = {JH1 * F_IN, JH1, JH1 * F_IN, JH1, H1 * CH, JH1,
                         JH2 * JH1, JH2, JH2 * JH1, JH2, JH2, JH2};
        int c = 0;
        for (int s = 0; s < 12; s++) { a.src[s] = d_in[2 + s]; a.cum[s] = c; c += sizes[s]; }
        a.cum[12] = c;
        cvt_weights<<<(W_TOTAL + 255) / 256, 256, 0, stream>>>(a, Wc, W_TOTAL, flag);
    }

    // 2) CSR by dst (shared by both layers); NB blocks of 1024 elems
    const int NB = (NN + 1023) / 1024;   // 49 for NN=50000 (<=256 supported)
    hipMemsetAsync(deg, 0, (size_t)NN * 4, stream);
    build_deg<<<(EP + 255) / 256, 256, 0, stream>>>(ei, deg, EE, NN);
    scan_part<<<NB, 256, 0, stream>>>(deg, bsum, NN);
    scan_block<<<1, 256, 0, stream>>>(bsum, boff, rowp + NN, NB);
    scan_final<<<NB, 256, 0, stream>>>(deg, boff, rowp, cur, NN);
    scatter_edges<<<(EP + 255) / 256, 256, 0, stream>>>(ei, cur, col, EE, NN);

    // 3) layer 1
    {
        dim3 grid((NN + 127) / 128, JT1 / 64);
        gemm_mfma<F_IN><<<grid, 256, 0, stream>>>(XC, Wc + W_WL1, Wc + W_WR1,
                                                  Wc + W_BL1, Wc + W_BR1, Y1, NN, JH1);
    }
    agg1<<<(NN + 3) / 4, 256, 0, stream>>>(Y1, rowp, col, Wc + W_ATT1,
                                           Wc + W_BIAS1, hbuf, NN);

    // 4) layer 2
    {
        dim3 grid((NN + 127) / 128, JT2 / 64);
        gemm_mfma<JH1><<<grid, 256, 0, stream>>>(hbuf, Wc + W_WL2, Wc + W_WR2,
                                                 Wc + W_BL2, Wc + W_BR2, Y2, NN, JH2);
    }
    agg2<<<(NN + 3) / 4, 256, 0, stream>>>(Y2, rowp, col, Wc + W_ATT2,
                                           Wc + W_BIAS2, d_out, NN, flag);
}